// Round 8
// baseline (254.683 us; speedup 1.0000x reference)
//
#include <hip/hip_runtime.h>
#include <hip/hip_bf16.h>

// Problem dims (fixed by reference setup)
#define B_   16
#define N_   8
#define C_   512
#define D_   768
#define HH   64
#define WW   64
#define HW   4096          // 64*64 pixels per batch

typedef __bf16 bf16;
typedef __attribute__((ext_vector_type(8))) __bf16 bf16x8;
typedef __attribute__((ext_vector_type(4))) __bf16 bf16x4;
typedef __attribute__((ext_vector_type(4))) float  f32x4;

// ---------------------------------------------------------------------------
// K_pre1: all-coalesced weight products.
// Blocks 0..127   : W2[o,c] = wo_w[o,:]·wv_w[:,c] (bf16), 4 o-rows per block;
//                   b2[o] = wo_w[o,:]·wv_b (threads c<4).
// Blocks 128..320 : WQK[d,m] = sum_o wq_w[o,d]·wk_w[o,m], 4 d-rows per block.
//                   Virtual row d==768 uses wq_b[o] (bias row).
__global__ __launch_bounds__(512) void k_pre1(const float* __restrict__ wq_w,
                                              const float* __restrict__ wq_b,
                                              const float* __restrict__ wk_w,
                                              const float* __restrict__ wo_w,
                                              const float* __restrict__ wv_w,
                                              const float* __restrict__ wv_b,
                                              float* __restrict__ WQK,
                                              bf16* __restrict__ W2,
                                              float* __restrict__ b2) {
    int tid = threadIdx.x;
    int blk = blockIdx.x;
    if (blk < 128) {
        int o0 = blk * 4;
        int c  = tid;
        const float* r0 = wo_w + (size_t)o0 * C_;     // uniform rows
        float a0 = 0.f, a1 = 0.f, a2 = 0.f, a3 = 0.f;
        #pragma unroll 8
        for (int m = 0; m < C_; ++m) {
            float v = wv_w[(size_t)m * C_ + c];       // coalesced
            a0 = fmaf(r0[m],          v, a0);
            a1 = fmaf(r0[C_ + m],     v, a1);
            a2 = fmaf(r0[2 * C_ + m], v, a2);
            a3 = fmaf(r0[3 * C_ + m], v, a3);
        }
        W2[(size_t)(o0 + 0) * C_ + c] = (bf16)a0;
        W2[(size_t)(o0 + 1) * C_ + c] = (bf16)a1;
        W2[(size_t)(o0 + 2) * C_ + c] = (bf16)a2;
        W2[(size_t)(o0 + 3) * C_ + c] = (bf16)a3;
        if (c < 4) {
            float sb = 0.f;
            const float* rr = wo_w + (size_t)(o0 + c) * C_;
            #pragma unroll 4
            for (int m = 0; m < C_; ++m) sb = fmaf(rr[m], wv_b[m], sb);
            b2[o0 + c] = sb;
        }
    } else {
        int d0 = (blk - 128) * 4;                     // 0..768
        int m  = tid;
        // per-row scalar source: d<768 -> wq_w column d (stride 768); d==768 -> wq_b
        const float* s0 = (d0 + 0 < D_) ? wq_w + d0 + 0 : wq_b;
        const float* s1 = (d0 + 1 < D_) ? wq_w + d0 + 1 : wq_b;
        const float* s2 = (d0 + 2 < D_) ? wq_w + d0 + 2 : wq_b;
        const float* s3 = (d0 + 3 < D_) ? wq_w + d0 + 3 : wq_b;
        int t0 = (d0 + 0 < D_) ? D_ : 1;
        int t1 = (d0 + 1 < D_) ? D_ : 1;
        int t2 = (d0 + 2 < D_) ? D_ : 1;
        int t3 = (d0 + 3 < D_) ? D_ : 1;
        float a0 = 0.f, a1 = 0.f, a2 = 0.f, a3 = 0.f;
        #pragma unroll 4
        for (int o = 0; o < C_; ++o) {
            float w = wk_w[(size_t)o * C_ + m];       // coalesced
            a0 = fmaf(s0[(size_t)o * t0], w, a0);     // uniform scalar
            a1 = fmaf(s1[(size_t)o * t1], w, a1);
            a2 = fmaf(s2[(size_t)o * t2], w, a2);
            a3 = fmaf(s3[(size_t)o * t3], w, a3);
        }
        if (d0 + 0 <= D_) WQK[(size_t)(d0 + 0) * C_ + m] = a0;
        if (d0 + 1 <= D_) WQK[(size_t)(d0 + 1) * C_ + m] = a1;
        if (d0 + 2 <= D_) WQK[(size_t)(d0 + 2) * C_ + m] = a2;
        if (d0 + 3 <= D_) WQK[(size_t)(d0 + 3) * C_ + m] = a3;
    }
}

// ---------------------------------------------------------------------------
// K_pre2: Qkb[b,n',m] = bf16( (sum_d we[d]·WQK[d,m] + WQK[768,m]) / sqrt(768) )
// grid 512 = (b,n',half), block 256 (thread = m within half); rows n'>=8 zero.
__global__ __launch_bounds__(256) void k_pre2(const float* __restrict__ se,
                                              const float* __restrict__ weights,
                                              const float* __restrict__ WQK,
                                              bf16* __restrict__ Qkb) {
    int blk  = blockIdx.x;
    int half = blk & 1, bn16 = blk >> 1;
    int b = bn16 >> 4, n = bn16 & 15;
    int m = half * 256 + threadIdx.x;
    if (n >= 8) {                                     // zero padding rows
        Qkb[(size_t)bn16 * C_ + m] = (bf16)0.f;
        return;
    }
    const float* se_row = se + (size_t)(b * N_ + n) * D_;
    float wt = weights[n];
    float acc = WQK[(size_t)D_ * C_ + m];             // bias row
    #pragma unroll 8
    for (int d = 0; d < D_; ++d)
        acc = fmaf(se_row[d] * wt, WQK[(size_t)d * C_ + m], acc);
    Qkb[(size_t)bn16 * C_ + m] = (bf16)(acc * 3.6084391824351615e-2f);
}

// ---------------------------------------------------------------------------
// K2 (fused v4): per block (b, pt): full-M GEMM over 128-pixel panel with
// PERSISTENT bf16 B-panel in LDS (doubles as the residual source):
//   Bp[128 p][512 c] bf16 (128KB, XOR-swizzled) -- written once per K-slice
//   Al[512 o][32 c]  bf16 (32KB, single-buffered, BK=32)
//   acc[o,p] += W2·x ; scores via MFMA on shared B frags; in-register softmax;
//   out = bf16(x) + wo_b + s*(acc + b2)   (residual read back from Bp)
// T14 reg-staging: A issued 1 tile ahead (L2 cover = MFMA phase), B issued
// 2 tiles ahead (HBM cover = 2 phases), static even/odd register sets.

__global__ __launch_bounds__(512, 2) void k_fused(const float* __restrict__ x,
                                                  const bf16* __restrict__ W2,
                                                  const float* __restrict__ b2,
                                                  const float* __restrict__ wo_b,
                                                  const bf16* __restrict__ Qkb,
                                                  float* __restrict__ out) {
    // XCD swizzle (512 % 8 == 0 -> bijective)
    int id = blockIdx.x;
    int job = (id & 7) * 64 + (id >> 3);          // 0..511
    int b = job >> 5, pt = job & 31;
    int p0 = pt * 128;                            // 2 complete h-rows

    __shared__ __align__(128) unsigned char Bp[131072]; // [128 p][512 c] bf16 swz
    __shared__ __align__(128) unsigned char Al[32768];  // [512 o][32 c] bf16 swz

    int tid = threadIdx.x;
    int wid = tid >> 6, lane = tid & 63;
    int wm = wid >> 1, wp = wid & 1;

    // B-stage role: thread owns ONE pixel, 8 channels per tile
    int pg = tid & 127, cg = tid >> 7;            // pixel, c-octet
    int fB = (pg & 63) << 4;                      // full-slot swizzle
    // A-stage role: thread owns 4 rows (one per 128-row group), 16B slot
    int r0 = tid >> 2, sl = tid & 3;
    int fA = ((r0 >> 1) & 3) << 4;

    f32x4 acc[8][4] = {};
    f32x4 acc_q[4] = {};

    const float* xb = x + (size_t)b * C_ * HW + p0 + pg;

    bf16x8 ar[4];
    float bvA[8], bvB[8];

#define ISSUE_A(K0)                                                           \
    { _Pragma("unroll")                                                       \
      for (int q = 0; q < 4; ++q)                                            \
          ar[q] = *(const bf16x8*)(W2 + (size_t)(q*128 + r0) * C_ + (K0) + sl*8); }

#define ISSUE_B(K0, BV)                                                       \
    { _Pragma("unroll")                                                       \
      for (int i = 0; i < 8; ++i)                                            \
          BV[i] = xb[(size_t)((K0) + cg*8 + i) * HW]; }

#define STAGE_WRITE(K0, BV)                                                   \
    { _Pragma("unroll")                                                       \
      for (int q = 0; q < 4; ++q)                                            \
          *(bf16x8*)(&Al[(q*128 + r0)*64 + ((sl*16) ^ fA)]) = ar[q];          \
      bf16x8 bw;                                                              \
      _Pragma("unroll")                                                       \
      for (int i = 0; i < 8; ++i) bw[i] = (bf16)BV[i];                        \
      *(bf16x8*)(&Bp[pg*1024 + ((((K0)*2) + cg*16) ^ fB)]) = bw; }

#define MFMA_TILE(K0)                                                         \
    { int kb = (K0)*2 + ((lane>>4)<<4);                                       \
      bf16x8 bbf[4];                                                          \
      _Pragma("unroll")                                                       \
      for (int j = 0; j < 4; ++j) {                                          \
          int row = wp*64 + j*16 + (lane&15);                                 \
          bbf[j] = *(const bf16x8*)(&Bp[row*1024 + (kb ^ ((row&63)<<4))]);    \
      }                                                                       \
      __builtin_amdgcn_s_setprio(1);                                          \
      _Pragma("unroll")                                                       \
      for (int i = 0; i < 8; ++i) {                                          \
          int row = wm*128 + i*16 + (lane&15);                                \
          bf16x8 av = *(const bf16x8*)(&Al[row*64 +                           \
                          (((lane>>4)<<4) ^ (((row>>1)&3)<<4))]);             \
          _Pragma("unroll")                                                   \
          for (int j = 0; j < 4; ++j)                                        \
              acc[i][j] = __builtin_amdgcn_mfma_f32_16x16x32_bf16(            \
                              av, bbf[j], acc[i][j], 0, 0, 0);                \
      }                                                                       \
      if (wm == 0) {                                                          \
          bf16x8 aq = *(const bf16x8*)(Qkb + ((size_t)b*16 + (lane&15))*C_    \
                                        + (K0) + ((lane>>4)<<3));             \
          _Pragma("unroll")                                                   \
          for (int j = 0; j < 4; ++j)                                        \
              acc_q[j] = __builtin_amdgcn_mfma_f32_16x16x32_bf16(             \
                             aq, bbf[j], acc_q[j], 0, 0, 0);                  \
      }                                                                       \
      __builtin_amdgcn_s_setprio(0); }

    // ---- prologue: A(0), B(0), B(1) in flight ----
    ISSUE_A(0);
    ISSUE_B(0,  bvA);
    ISSUE_B(32, bvB);

    #pragma unroll 1
    for (int tt = 0; tt < 8; ++tt) {
        int k0 = tt * 64;
        // ---- even tile (k0), consumes bvA ----
        STAGE_WRITE(k0, bvA);                     // compiler waits vmcnt for ar/bvA
        asm volatile("s_waitcnt lgkmcnt(0)" ::: "memory");
        __builtin_amdgcn_s_barrier();
        ISSUE_A(k0 + 32);                         // 1 tile ahead (L2)
        if (tt < 7) ISSUE_B(k0 + 64, bvA);        // 2 tiles ahead (HBM)
        MFMA_TILE(k0);
        __builtin_amdgcn_s_barrier();             // Al/Bp reads done
        // ---- odd tile (k0+32), consumes bvB ----
        STAGE_WRITE(k0 + 32, bvB);
        asm volatile("s_waitcnt lgkmcnt(0)" ::: "memory");
        __builtin_amdgcn_s_barrier();
        if (tt < 7) { ISSUE_A(k0 + 64); ISSUE_B(k0 + 96, bvB); }
        MFMA_TILE(k0 + 32);
        __builtin_amdgcn_s_barrier();
    }

    // ---- in-register softmax over w (64 px) on waves 0,1 ----
    float* s_lds = (float*)Al;                    // Al is dead now
    if (wm == 0) {
        float sm[4];
        #pragma unroll
        for (int r = 0; r < 4; ++r) {
            float m = fmaxf(fmaxf(acc_q[0][r], acc_q[1][r]),
                            fmaxf(acc_q[2][r], acc_q[3][r]));
            #pragma unroll
            for (int off = 1; off <= 8; off <<= 1) m = fmaxf(m, __shfl_xor(m, off));
            float s = 0.f;
            #pragma unroll
            for (int j = 0; j < 4; ++j) { acc_q[j][r] = __expf(acc_q[j][r] - m); s += acc_q[j][r]; }
            #pragma unroll
            for (int off = 1; off <= 8; off <<= 1) s += __shfl_xor(s, off);
            sm[r] = s;
        }
        f32x4 rcp;
        #pragma unroll
        for (int r = 0; r < 4; ++r) rcp[r] = 1.f / sm[r];
        #pragma unroll
        for (int j = 0; j < 4; ++j) {
            float sp = acc_q[j][0]*rcp[0] + acc_q[j][1]*rcp[1]
                     + acc_q[j][2]*rcp[2] + acc_q[j][3]*rcp[3];
            sp += __shfl_xor(sp, 16);             // add the other n-quad
            if (lane < 16) s_lds[wp*64 + j*16 + lane] = sp;
        }
    }
    __syncthreads();

    // ---- epilogue: out = bf16(x) + wo_b + s*(acc + b2); residual from Bp ----
    int r4 = (lane >> 4) << 2;
    int cl = lane & 15;
    #pragma unroll
    for (int j = 0; j < 4; ++j) {
        int pl = wp * 64 + j * 16 + cl;
        float sv = s_lds[pl];
        int fBp = (pl & 63) << 4;
        #pragma unroll
        for (int i = 0; i < 8; ++i) {
            int ob = wm * 128 + i * 16 + r4;
            f32x4 b2v = *(const f32x4*)(b2 + ob);
            f32x4 wbv = *(const f32x4*)(wo_b + ob);
            bf16x4 rx = *(const bf16x4*)(&Bp[pl*1024 + ((ob*2) ^ fBp)]);
            #pragma unroll
            for (int r = 0; r < 4; ++r) {
                size_t gi = ((size_t)b * C_ + ob + r) * HW + p0 + pl;
                out[gi] = (float)rx[r] + wbv[r] + sv * (acc[i][j][r] + b2v[r]);
            }
        }
    }
#undef ISSUE_A
#undef ISSUE_B
#undef STAGE_WRITE
#undef MFMA_TILE
}

// ---------------------------------------------------------------------------
extern "C" void kernel_launch(void* const* d_in, const int* in_sizes, int n_in,
                              void* d_out, int out_size, void* d_ws, size_t ws_size,
                              hipStream_t stream) {
    const float* x    = (const float*)d_in[0];
    const float* se   = (const float*)d_in[1];
    const float* wts  = (const float*)d_in[2];
    const float* wq_w = (const float*)d_in[3];
    const float* wq_b = (const float*)d_in[4];
    const float* wk_w = (const float*)d_in[5];
    // d_in[6] = wk_b: constant over softmax axis -> cancels, unused
    const float* wv_w = (const float*)d_in[7];
    const float* wv_b = (const float*)d_in[8];
    const float* wo_w = (const float*)d_in[9];
    const float* wo_b = (const float*)d_in[10];
    float* out = (float*)d_out;

    // workspace layout (~2.4MB)
    char* ws = (char*)d_ws;
    bf16*  Qkb = (bf16*) (ws + 0);          // 256KB  [16][16][512], rows 8..15 zero
    bf16*  W2  = (bf16*) (ws + 262144);     // 512KB
    float* b2  = (float*)(ws + 786432);     // 2KB
    float* WQK = (float*)(ws + 790528);     // 1.58MB [769][512] (row 768 = bias)

    k_pre1  <<<dim3(321), dim3(512), 0, stream>>>(wq_w, wq_b, wk_w,
                                                  wo_w, wv_w, wv_b, WQK, W2, b2);
    k_pre2  <<<dim3(512), dim3(256), 0, stream>>>(se, wts, WQK, Qkb);
    k_fused <<<dim3(512), dim3(512), 0, stream>>>(x, W2, b2, wo_b, Qkb, out);
}

// Round 9
// 155.851 us; speedup vs baseline: 1.6341x; 1.6341x over previous
//
#include <hip/hip_runtime.h>
#include <hip/hip_bf16.h>

// Problem dims (fixed by reference setup)
#define B_   16
#define N_   8
#define C_   512
#define D_   768
#define HH   64
#define WW   64
#define HW   4096          // 64*64 pixels per batch

typedef __bf16 bf16;
typedef __attribute__((ext_vector_type(8))) __bf16 bf16x8;
typedef __attribute__((ext_vector_type(4))) __bf16 bf16x4;
typedef __attribute__((ext_vector_type(4))) float  f32x4;

// ---------------------------------------------------------------------------
// K_tw2: blocks 0..95: LDS-tiled transpose wq_w(512x768) -> wqT(768x512).
//        blocks 96..351: W2[o,c] = wo_w[o,:]·wv_w[:,c] (bf16), 4 o-rows x
//        c-half per block; b2[o] = wo_w[o,:]·wv_b on half-0 blocks.
__global__ __launch_bounds__(256) void k_tw2(const float* __restrict__ wq_w,
                                             const float* __restrict__ wo_w,
                                             const float* __restrict__ wv_w,
                                             const float* __restrict__ wv_b,
                                             float* __restrict__ wqT,
                                             bf16* __restrict__ W2,
                                             float* __restrict__ b2) {
    int tid = threadIdx.x;
    int blk = blockIdx.x;
    if (blk < 96) {
        // 64x64 tile transpose: tile (tc, td); 8 c-tiles x 12 d-tiles
        int tc = blk & 7, td = blk >> 3;
        int c0 = tc * 64, d0 = td * 64;
        __shared__ float tile[64][65];
        int row = tid >> 2, seg = tid & 3;
        const float* src = wq_w + (size_t)(c0 + row) * D_ + d0 + seg * 16;
        #pragma unroll
        for (int i = 0; i < 4; ++i) {
            f32x4 v = *(const f32x4*)(src + i * 4);
            tile[row][seg * 16 + i * 4 + 0] = v[0];
            tile[row][seg * 16 + i * 4 + 1] = v[1];
            tile[row][seg * 16 + i * 4 + 2] = v[2];
            tile[row][seg * 16 + i * 4 + 3] = v[3];
        }
        __syncthreads();
        float* dst = wqT + (size_t)(d0 + row) * C_ + c0 + seg * 16;
        #pragma unroll
        for (int i = 0; i < 4; ++i) {
            f32x4 v;
            v[0] = tile[seg * 16 + i * 4 + 0][row];
            v[1] = tile[seg * 16 + i * 4 + 1][row];
            v[2] = tile[seg * 16 + i * 4 + 2][row];
            v[3] = tile[seg * 16 + i * 4 + 3][row];
            *(f32x4*)(dst + i * 4) = v;
        }
    } else {
        int blk2 = blk - 96;                          // 0..255
        int o0 = (blk2 >> 1) * 4;
        int c  = (blk2 & 1) * 256 + tid;
        const float* r0 = wo_w + (size_t)o0 * C_;     // uniform rows (scalar)
        float a0 = 0.f, a1 = 0.f, a2 = 0.f, a3 = 0.f;
        #pragma unroll 8
        for (int m = 0; m < C_; ++m) {
            float v = wv_w[(size_t)m * C_ + c];       // coalesced
            a0 = fmaf(r0[m],          v, a0);
            a1 = fmaf(r0[C_ + m],     v, a1);
            a2 = fmaf(r0[2 * C_ + m], v, a2);
            a3 = fmaf(r0[3 * C_ + m], v, a3);
        }
        W2[(size_t)(o0 + 0) * C_ + c] = (bf16)a0;
        W2[(size_t)(o0 + 1) * C_ + c] = (bf16)a1;
        W2[(size_t)(o0 + 2) * C_ + c] = (bf16)a2;
        W2[(size_t)(o0 + 3) * C_ + c] = (bf16)a3;
        if ((blk2 & 1) == 0 && tid < 4) {
            float sb = 0.f;
            const float* rr = wo_w + (size_t)(o0 + tid) * C_;
            #pragma unroll 4
            for (int m = 0; m < C_; ++m) sb = fmaf(rr[m], wv_b[m], sb);
            b2[o0 + tid] = sb;
        }
    }
}

// ---------------------------------------------------------------------------
// K_q: Q[bn,c] = weights[n]*sum_d se[bn,d]*wqT[d,c] + wq_b[c]
// grid 512 = (bn, c-quarter), block 128.  se scalar (sequential), wqT coalesced.
__global__ __launch_bounds__(128) void k_q(const float* __restrict__ se,
                                           const float* __restrict__ weights,
                                           const float* __restrict__ wqT,
                                           const float* __restrict__ wq_b,
                                           float* __restrict__ Q) {
    int blk = blockIdx.x;
    int bn = blk >> 2, q = blk & 3;
    int c = q * 128 + threadIdx.x;
    const float* se_row = se + (size_t)bn * D_;       // uniform
    float wt = weights[bn & 7];
    float a0 = 0.f, a1 = 0.f, a2 = 0.f, a3 = 0.f;
    #pragma unroll 4
    for (int d = 0; d < D_; d += 4) {
        a0 = fmaf(se_row[d + 0], wqT[(size_t)(d + 0) * C_ + c], a0);
        a1 = fmaf(se_row[d + 1], wqT[(size_t)(d + 1) * C_ + c], a1);
        a2 = fmaf(se_row[d + 2], wqT[(size_t)(d + 2) * C_ + c], a2);
        a3 = fmaf(se_row[d + 3], wqT[(size_t)(d + 3) * C_ + c], a3);
    }
    Q[(size_t)bn * C_ + c] = wt * ((a0 + a1) + (a2 + a3)) + wq_b[c];
}

// ---------------------------------------------------------------------------
// K_qk: Qkb[b,n',m] = bf16( (sum_o Q[bn,o]*wk_w[o,m]) / sqrt(768) ), n'>=8 zero.
// grid 512 = (bn16, m-half), block 256.  Q scalar (sequential), wk_w coalesced.
__global__ __launch_bounds__(256) void k_qk(const float* __restrict__ Q,
                                            const float* __restrict__ wk_w,
                                            bf16* __restrict__ Qkb) {
    int blk = blockIdx.x;
    int bn16 = blk >> 1, half = blk & 1;
    int b = bn16 >> 4, n = bn16 & 15;
    int m = half * 256 + threadIdx.x;
    if (n >= 8) {                                     // zero padding rows
        Qkb[(size_t)bn16 * C_ + m] = (bf16)0.f;
        return;
    }
    const float* q = Q + (size_t)(b * N_ + n) * C_;   // uniform
    float a0 = 0.f, a1 = 0.f, a2 = 0.f, a3 = 0.f;
    #pragma unroll 4
    for (int o = 0; o < C_; o += 4) {
        a0 = fmaf(q[o + 0], wk_w[(size_t)(o + 0) * C_ + m], a0);
        a1 = fmaf(q[o + 1], wk_w[(size_t)(o + 1) * C_ + m], a1);
        a2 = fmaf(q[o + 2], wk_w[(size_t)(o + 2) * C_ + m], a2);
        a3 = fmaf(q[o + 3], wk_w[(size_t)(o + 3) * C_ + m], a3);
    }
    Qkb[(size_t)bn16 * C_ + m] =
        (bf16)(((a0 + a1) + (a2 + a3)) * 3.6084391824351615e-2f);
}

// ---------------------------------------------------------------------------
// K2 (fused v4): per block (b, pt): full-M GEMM over 128-pixel panel with
// PERSISTENT bf16 B-panel in LDS (doubles as the residual source):
//   Bp[128 p][512 c] bf16 (128KB, XOR-swizzled) -- written once per K-slice
//   Al[512 o][32 c]  bf16 (32KB, single-buffered, BK=32)
//   acc[o,p] += W2·x ; scores via MFMA on shared B frags; in-register softmax;
//   out = bf16(x) + wo_b + s*(acc + b2)   (residual read back from Bp)
// T14 reg-staging: A issued 1 tile ahead (L2 cover = MFMA phase), B issued
// 2 tiles ahead (HBM cover = 2 phases), static even/odd register sets.

__global__ __launch_bounds__(512, 2) void k_fused(const float* __restrict__ x,
                                                  const bf16* __restrict__ W2,
                                                  const float* __restrict__ b2,
                                                  const float* __restrict__ wo_b,
                                                  const bf16* __restrict__ Qkb,
                                                  float* __restrict__ out) {
    // XCD swizzle (512 % 8 == 0 -> bijective)
    int id = blockIdx.x;
    int job = (id & 7) * 64 + (id >> 3);          // 0..511
    int b = job >> 5, pt = job & 31;
    int p0 = pt * 128;                            // 2 complete h-rows

    __shared__ __align__(128) unsigned char Bp[131072]; // [128 p][512 c] bf16 swz
    __shared__ __align__(128) unsigned char Al[32768];  // [512 o][32 c] bf16 swz

    int tid = threadIdx.x;
    int wid = tid >> 6, lane = tid & 63;
    int wm = wid >> 1, wp = wid & 1;

    // B-stage role: thread owns ONE pixel, 8 channels per tile
    int pg = tid & 127, cg = tid >> 7;            // pixel, c-octet
    int fB = (pg & 63) << 4;                      // full-slot swizzle
    // A-stage role: thread owns 4 rows (one per 128-row group), 16B slot
    int r0 = tid >> 2, sl = tid & 3;
    int fA = ((r0 >> 1) & 3) << 4;

    f32x4 acc[8][4] = {};
    f32x4 acc_q[4] = {};

    const float* xb = x + (size_t)b * C_ * HW + p0 + pg;

    bf16x8 ar[4];
    float bvA[8], bvB[8];

#define ISSUE_A(K0)                                                           \
    { _Pragma("unroll")                                                       \
      for (int q = 0; q < 4; ++q)                                            \
          ar[q] = *(const bf16x8*)(W2 + (size_t)(q*128 + r0) * C_ + (K0) + sl*8); }

#define ISSUE_B(K0, BV)                                                       \
    { _Pragma("unroll")                                                       \
      for (int i = 0; i < 8; ++i)                                            \
          BV[i] = xb[(size_t)((K0) + cg*8 + i) * HW]; }

#define STAGE_WRITE(K0, BV)                                                   \
    { _Pragma("unroll")                                                       \
      for (int q = 0; q < 4; ++q)                                            \
          *(bf16x8*)(&Al[(q*128 + r0)*64 + ((sl*16) ^ fA)]) = ar[q];          \
      bf16x8 bw;                                                              \
      _Pragma("unroll")                                                       \
      for (int i = 0; i < 8; ++i) bw[i] = (bf16)BV[i];                        \
      *(bf16x8*)(&Bp[pg*1024 + ((((K0)*2) + cg*16) ^ fB)]) = bw; }

#define MFMA_TILE(K0)                                                         \
    { int kb = (K0)*2 + ((lane>>4)<<4);                                       \
      bf16x8 bbf[4];                                                          \
      _Pragma("unroll")                                                       \
      for (int j = 0; j < 4; ++j) {                                          \
          int row = wp*64 + j*16 + (lane&15);                                 \
          bbf[j] = *(const bf16x8*)(&Bp[row*1024 + (kb ^ ((row&63)<<4))]);    \
      }                                                                       \
      __builtin_amdgcn_s_setprio(1);                                          \
      _Pragma("unroll")                                                       \
      for (int i = 0; i < 8; ++i) {                                          \
          int row = wm*128 + i*16 + (lane&15);                                \
          bf16x8 av = *(const bf16x8*)(&Al[row*64 +                           \
                          (((lane>>4)<<4) ^ (((row>>1)&3)<<4))]);             \
          _Pragma("unroll")                                                   \
          for (int j = 0; j < 4; ++j)                                        \
              acc[i][j] = __builtin_amdgcn_mfma_f32_16x16x32_bf16(            \
                              av, bbf[j], acc[i][j], 0, 0, 0);                \
      }                                                                       \
      if (wm == 0) {                                                          \
          bf16x8 aq = *(const bf16x8*)(Qkb + ((size_t)b*16 + (lane&15))*C_    \
                                        + (K0) + ((lane>>4)<<3));             \
          _Pragma("unroll")                                                   \
          for (int j = 0; j < 4; ++j)                                        \
              acc_q[j] = __builtin_amdgcn_mfma_f32_16x16x32_bf16(             \
                             aq, bbf[j], acc_q[j], 0, 0, 0);                  \
      }                                                                       \
      __builtin_amdgcn_s_setprio(0); }

    // ---- prologue: A(0), B(0), B(1) in flight ----
    ISSUE_A(0);
    ISSUE_B(0,  bvA);
    ISSUE_B(32, bvB);

    #pragma unroll 1
    for (int tt = 0; tt < 8; ++tt) {
        int k0 = tt * 64;
        // ---- even tile (k0), consumes bvA ----
        STAGE_WRITE(k0, bvA);                     // compiler waits vmcnt for ar/bvA
        asm volatile("s_waitcnt lgkmcnt(0)" ::: "memory");
        __builtin_amdgcn_s_barrier();
        ISSUE_A(k0 + 32);                         // 1 tile ahead (L2)
        if (tt < 7) ISSUE_B(k0 + 64, bvA);        // 2 tiles ahead (HBM)
        MFMA_TILE(k0);
        __builtin_amdgcn_s_barrier();             // Al/Bp reads done
        // ---- odd tile (k0+32), consumes bvB ----
        STAGE_WRITE(k0 + 32, bvB);
        asm volatile("s_waitcnt lgkmcnt(0)" ::: "memory");
        __builtin_amdgcn_s_barrier();
        if (tt < 7) { ISSUE_A(k0 + 64); ISSUE_B(k0 + 96, bvB); }
        MFMA_TILE(k0 + 32);
        __builtin_amdgcn_s_barrier();
    }

    // ---- in-register softmax over w (64 px) on waves 0,1 ----
    float* s_lds = (float*)Al;                    // Al is dead now
    if (wm == 0) {
        float sm[4];
        #pragma unroll
        for (int r = 0; r < 4; ++r) {
            float m = fmaxf(fmaxf(acc_q[0][r], acc_q[1][r]),
                            fmaxf(acc_q[2][r], acc_q[3][r]));
            #pragma unroll
            for (int off = 1; off <= 8; off <<= 1) m = fmaxf(m, __shfl_xor(m, off));
            float s = 0.f;
            #pragma unroll
            for (int j = 0; j < 4; ++j) { acc_q[j][r] = __expf(acc_q[j][r] - m); s += acc_q[j][r]; }
            #pragma unroll
            for (int off = 1; off <= 8; off <<= 1) s += __shfl_xor(s, off);
            sm[r] = s;
        }
        f32x4 rcp;
        #pragma unroll
        for (int r = 0; r < 4; ++r) rcp[r] = 1.f / sm[r];
        #pragma unroll
        for (int j = 0; j < 4; ++j) {
            float sp = acc_q[j][0]*rcp[0] + acc_q[j][1]*rcp[1]
                     + acc_q[j][2]*rcp[2] + acc_q[j][3]*rcp[3];
            sp += __shfl_xor(sp, 16);             // add the other n-quad
            if (lane < 16) s_lds[wp*64 + j*16 + lane] = sp;
        }
    }
    __syncthreads();

    // ---- epilogue: out = bf16(x) + wo_b + s*(acc + b2); residual from Bp ----
    int r4 = (lane >> 4) << 2;
    int cl = lane & 15;
    #pragma unroll
    for (int j = 0; j < 4; ++j) {
        int pl = wp * 64 + j * 16 + cl;
        float sv = s_lds[pl];
        int fBp = (pl & 63) << 4;
        #pragma unroll
        for (int i = 0; i < 8; ++i) {
            int ob = wm * 128 + i * 16 + r4;
            f32x4 b2v = *(const f32x4*)(b2 + ob);
            f32x4 wbv = *(const f32x4*)(wo_b + ob);
            bf16x4 rx = *(const bf16x4*)(&Bp[pl*1024 + ((ob*2) ^ fBp)]);
            #pragma unroll
            for (int r = 0; r < 4; ++r) {
                size_t gi = ((size_t)b * C_ + ob + r) * HW + p0 + pl;
                out[gi] = (float)rx[r] + wbv[r] + sv * (acc[i][j][r] + b2v[r]);
            }
        }
    }
#undef ISSUE_A
#undef ISSUE_B
#undef STAGE_WRITE
#undef MFMA_TILE
}

// ---------------------------------------------------------------------------
extern "C" void kernel_launch(void* const* d_in, const int* in_sizes, int n_in,
                              void* d_out, int out_size, void* d_ws, size_t ws_size,
                              hipStream_t stream) {
    const float* x    = (const float*)d_in[0];
    const float* se   = (const float*)d_in[1];
    const float* wts  = (const float*)d_in[2];
    const float* wq_w = (const float*)d_in[3];
    const float* wq_b = (const float*)d_in[4];
    const float* wk_w = (const float*)d_in[5];
    // d_in[6] = wk_b: constant over softmax axis -> cancels, unused
    const float* wv_w = (const float*)d_in[7];
    const float* wv_b = (const float*)d_in[8];
    const float* wo_w = (const float*)d_in[9];
    const float* wo_b = (const float*)d_in[10];
    float* out = (float*)d_out;

    // workspace layout (~2.6MB)
    char* ws = (char*)d_ws;
    bf16*  Qkb = (bf16*) (ws + 0);          // 256KB [16][16][512], rows 8..15 zero
    bf16*  W2  = (bf16*) (ws + 262144);     // 512KB
    float* b2  = (float*)(ws + 786432);     // 2KB
    float* wqT = (float*)(ws + 790528);     // 1.5MB [768][512]
    float* Q   = (float*)(ws + 2363392);    // 256KB [128][512]

    k_tw2   <<<dim3(352), dim3(256), 0, stream>>>(wq_w, wo_w, wv_w, wv_b,
                                                  wqT, W2, b2);
    k_q     <<<dim3(512), dim3(128), 0, stream>>>(se, wts, wqT, wq_b, Q);
    k_qk    <<<dim3(512), dim3(256), 0, stream>>>(Q, wk_w, Qkb);
    k_fused <<<dim3(512), dim3(512), 0, stream>>>(x, W2, b2, wo_b, Qkb, out);
}